// Round 3
// baseline (450.112 us; speedup 1.0000x reference)
//
#include <hip/hip_runtime.h>
#include <hip/hip_bf16.h>

// ---------------------------------------------------------------------------
// MoE dense all-expert forward, MI355X / gfx950.  B=16384, D=H=O=256, E=32.
// Round 3 = round-2 crew-pipelined design with the bit_cast compile fix.
//  k0: cvt_w   : W1,W2 f32 -> bf16 (one launch)
//  k1: gating  : f32 softmax top-22 weights -> ws; bias2 combine -> d_out
//  k2: moe     : 256 blocks x 512 thr (8 waves), block = 64 batch rows.
//      waves 0-3 (G1 crew): h(e)^T = W1[e] . x^T   (64 H x 64 rows each)
//      waves 4-7 (G2 crew): out^T += W2[e-1] . h(e-1)^T   (64 O x 64 rows)
//      2 barriers/expert, weight-read redundancy 1, LDS/MFMA ratio 62%.
// ---------------------------------------------------------------------------

typedef __attribute__((ext_vector_type(8))) short bf16x8;   // 8 bf16 = 4 VGPRs
typedef __attribute__((ext_vector_type(4))) float f32x4;

__device__ __forceinline__ unsigned short f2bf(float f) {
    unsigned u = __builtin_bit_cast(unsigned, f);
    u += 0x7FFFu + ((u >> 16) & 1u);        // round-to-nearest-even
    return (unsigned short)(u >> 16);
}
__device__ __forceinline__ unsigned pack_bf16x2(float a, float b) {
    return (unsigned)f2bf(a) | ((unsigned)f2bf(b) << 16);
}

// 16B-chunk XOR swizzle for [64 rows][256 elem] bf16 tiles (index in ushorts)
#define LX(r, ch) (((r) << 8) + ((((ch) ^ ((r) & 7))) << 3))

// --------------------------- W f32 -> bf16 convert -------------------------
__global__ __launch_bounds__(256) void cvt_w(const float* __restrict__ W1,
                                             const float* __restrict__ W2,
                                             unsigned short* __restrict__ W1b,
                                             unsigned short* __restrict__ W2b) {
    const int b = blockIdx.x;                       // 2048 blocks
    const float* src = (b < 1024) ? W1 : W2;
    unsigned short* dst = (b < 1024) ? W1b : W2b;
    int i = (b & 1023) * 256 + threadIdx.x;         // 8 elems per thread
    const float4* s = (const float4*)src + (long)i * 2;
    float4 v0 = s[0], v1 = s[1];
    uint4 o;
    o.x = pack_bf16x2(v0.x, v0.y); o.y = pack_bf16x2(v0.z, v0.w);
    o.z = pack_bf16x2(v1.x, v1.y); o.w = pack_bf16x2(v1.z, v1.w);
    ((uint4*)dst)[i] = o;
}

// ------------------------------- gating ------------------------------------
// 4 waves/block, one row per wave. All in f32 to match reference selection.
__global__ __launch_bounds__(256) void gating_kernel(
    const float* __restrict__ x, const float* __restrict__ Wg,
    const float* __restrict__ bg, const float* __restrict__ b2,
    float* __restrict__ wout, float* __restrict__ out)
{
    __shared__ float xrow[4][256];
    const int wave = threadIdx.x >> 6, lane = threadIdx.x & 63;
    const int row = blockIdx.x * 4 + wave;

    ((float4*)xrow[wave])[lane] = ((const float4*)(x + (long)row * 256))[lane];
    __syncthreads();

    const int e = lane & 31, half = lane >> 5;
    const float4* wg4 = (const float4*)(Wg + e * 256 + half * 128);
    const float4* xr4 = (const float4*)(&xrow[wave][half * 128]);
    float acc = 0.f;
#pragma unroll
    for (int i = 0; i < 32; ++i) {
        float4 w = wg4[i], xv = xr4[i];
        acc = fmaf(w.x, xv.x, acc); acc = fmaf(w.y, xv.y, acc);
        acc = fmaf(w.z, xv.z, acc); acc = fmaf(w.w, xv.w, acc);
    }
    acc += __shfl_xor(acc, 32);
    float score = (acc + bg[e]) / 2.71828182845904523f;   // TEMP = e

    float m = score;
#pragma unroll
    for (int d = 16; d >= 1; d >>= 1) m = fmaxf(m, __shfl_xor(m, d));
    float p = expf(score - m);
    float ps = p;
#pragma unroll
    for (int d = 16; d >= 1; d >>= 1) ps += __shfl_xor(ps, d);
    float prob = p / ps;

    int rank = 0;
#pragma unroll
    for (int j = 0; j < 32; ++j) {
        float pj = __shfl(prob, j);
        rank += (pj > prob || (pj == prob && j < e)) ? 1 : 0;
    }
    float kept = (rank < 22) ? prob : 0.f;
    float wsum = kept;
#pragma unroll
    for (int d = 16; d >= 1; d >>= 1) wsum += __shfl_xor(wsum, d);
    float weight = kept / (wsum + 1e-8f);

    if (half == 0) wout[(long)row * 32 + e] = weight;

    // bias2 row: sum_e w_e * b2[e,:]  -> d_out (accumulator init for moe)
    float4 a4 = {0.f, 0.f, 0.f, 0.f};
#pragma unroll
    for (int j = 0; j < 32; ++j) {
        float wj = __shfl(weight, j);
        float4 bv = ((const float4*)(b2 + j * 256))[lane];
        a4.x = fmaf(wj, bv.x, a4.x); a4.y = fmaf(wj, bv.y, a4.y);
        a4.z = fmaf(wj, bv.z, a4.z); a4.w = fmaf(wj, bv.w, a4.w);
    }
    ((float4*)(out + (long)row * 256))[lane] = a4;
}

// ------------------------------ fused MoE ----------------------------------
__global__ __launch_bounds__(512, 2) void moe_kernel(
    const float* __restrict__ x,
    const unsigned short* __restrict__ W1b,
    const unsigned short* __restrict__ W2b,
    const float* __restrict__ b1,
    const float* __restrict__ wgt,
    float* __restrict__ out)
{
    __shared__ __align__(16) unsigned short x_s[64 * 256];   // x tile, bf16
    __shared__ __align__(16) unsigned short h_s[64 * 256];   // h tile, bf16

    const int tid  = threadIdx.x;
    const int wv   = tid >> 6, lane = tid & 63;
    const int quad = lane >> 4, l15 = lane & 15;
    const int crew = wv >> 2, g = wv & 3;       // crew0 = G1, crew1 = G2
    const int row0 = blockIdx.x * 64;

    // ---- stage x tile: f32 global -> bf16 LDS (swizzled) ----
#pragma unroll
    for (int c = 0; c < 4; ++c) {
        int chunk = tid + c * 512;              // 2048 chunks of 8 elems
        int r = chunk >> 5, ch = chunk & 31;
        const float4* s = (const float4*)(x + (long)(row0 + r) * 256 + ch * 8);
        float4 v0 = s[0], v1 = s[1];
        uint4 o;
        o.x = pack_bf16x2(v0.x, v0.y); o.y = pack_bf16x2(v0.z, v0.w);
        o.z = pack_bf16x2(v1.x, v1.y); o.w = pack_bf16x2(v1.z, v1.w);
        *(uint4*)(&x_s[LX(r, ch)]) = o;
    }

    // ---- crew1: persistent out^T accumulators, init = bias2 from gating ----
    f32x4 oacc[4][4];                           // [ot][rt]
    if (crew == 1) {
#pragma unroll
        for (int ot = 0; ot < 4; ++ot)
#pragma unroll
            for (int rt = 0; rt < 4; ++rt)
                oacc[ot][rt] = *(const f32x4*)(out +
                    (long)(row0 + rt * 16 + l15) * 256 + g * 64 + ot * 16 + quad * 4);
    }
    __syncthreads();

    // ---- expert pipeline: G1(e) || G2(e-1), then G1 epilogue ----
    for (int e = 0; e <= 32; ++e) {
        f32x4 hacc[4][4];                       // crew0 transient [ht][rt]
        if (crew == 0) {
            if (e < 32) {
#pragma unroll
                for (int ht = 0; ht < 4; ++ht)
#pragma unroll
                    for (int rt = 0; rt < 4; ++rt) {
                        f32x4 z = {0.f, 0.f, 0.f, 0.f};
                        hacc[ht][rt] = z;
                    }
                const unsigned short* w1e =
                    W1b + (long)e * 65536 + (g * 64 + l15) * 256 + quad * 8;
#pragma unroll
                for (int kb = 0; kb < 8; ++kb) {
                    bf16x8 a[4], b[4];
#pragma unroll
                    for (int ht = 0; ht < 4; ++ht)
                        a[ht] = *(const bf16x8*)(w1e + ht * 16 * 256 + kb * 32);
#pragma unroll
                    for (int rt = 0; rt < 4; ++rt)
                        b[rt] = *(const bf16x8*)(&x_s[LX(rt * 16 + l15, kb * 4 + quad)]);
#pragma unroll
                    for (int ht = 0; ht < 4; ++ht)
#pragma unroll
                        for (int rt = 0; rt < 4; ++rt)
                            hacc[ht][rt] = __builtin_amdgcn_mfma_f32_16x16x32_bf16(
                                a[ht], b[rt], hacc[ht][rt], 0, 0, 0);
                }
            }
        } else {
            if (e > 0) {
                const unsigned short* w2e =
                    W2b + (long)(e - 1) * 65536 + (g * 64 + l15) * 256 + quad * 8;
#pragma unroll
                for (int kb = 0; kb < 8; ++kb) {
                    bf16x8 a[4], b[4];
#pragma unroll
                    for (int ot = 0; ot < 4; ++ot)
                        a[ot] = *(const bf16x8*)(w2e + ot * 16 * 256 + kb * 32);
#pragma unroll
                    for (int rt = 0; rt < 4; ++rt)
                        b[rt] = *(const bf16x8*)(&h_s[LX(rt * 16 + l15, kb * 4 + quad)]);
#pragma unroll
                    for (int ot = 0; ot < 4; ++ot)
#pragma unroll
                        for (int rt = 0; rt < 4; ++rt)
                            oacc[ot][rt] = __builtin_amdgcn_mfma_f32_16x16x32_bf16(
                                a[ot], b[rt], oacc[ot][rt], 0, 0, 0);
                }
            }
        }

        __syncthreads();   // G2(e-1) done reading h_s; G1(e) hacc ready

        if (crew == 0 && e < 32) {
            // epilogue: +b1, relu, * gate weight, packed b64 -> h_s
            float4 bv[4]; float gw[4];
#pragma unroll
            for (int ht = 0; ht < 4; ++ht)
                bv[ht] = *(const float4*)(b1 + e * 256 + g * 64 + ht * 16 + quad * 4);
#pragma unroll
            for (int rt = 0; rt < 4; ++rt)
                gw[rt] = wgt[(long)(row0 + rt * 16 + l15) * 32 + e];
#pragma unroll
            for (int ht = 0; ht < 4; ++ht) {
                int hb = g * 64 + ht * 16 + quad * 4;   // h-idx base (4 consecutive)
                int ch = hb >> 3, off = hb & 7;
#pragma unroll
                for (int rt = 0; rt < 4; ++rt) {
                    int r = rt * 16 + l15;
                    float v0 = fmaxf(hacc[ht][rt][0] + bv[ht].x, 0.f) * gw[rt];
                    float v1 = fmaxf(hacc[ht][rt][1] + bv[ht].y, 0.f) * gw[rt];
                    float v2 = fmaxf(hacc[ht][rt][2] + bv[ht].z, 0.f) * gw[rt];
                    float v3 = fmaxf(hacc[ht][rt][3] + bv[ht].w, 0.f) * gw[rt];
                    uint2 p;
                    p.x = pack_bf16x2(v0, v1);
                    p.y = pack_bf16x2(v2, v3);
                    *(uint2*)(&h_s[(r << 8) + (((ch) ^ (r & 7)) << 3) + off]) = p;
                }
            }
        }

        __syncthreads();   // h_s(e) final, visible to G2 next iteration
    }

    // ---- final store: out^T frags -> out, 16B per lane, 64B segments ----
    if (crew == 1) {
#pragma unroll
        for (int ot = 0; ot < 4; ++ot)
#pragma unroll
            for (int rt = 0; rt < 4; ++rt)
                *(f32x4*)(out + (long)(row0 + rt * 16 + l15) * 256 +
                          g * 64 + ot * 16 + quad * 4) = oacc[ot][rt];
    }
}

// ------------------------------- launch ------------------------------------
extern "C" void kernel_launch(void* const* d_in, const int* in_sizes, int n_in,
                              void* d_out, int out_size, void* d_ws, size_t ws_size,
                              hipStream_t stream) {
    (void)in_sizes; (void)n_in; (void)out_size; (void)ws_size;
    const float* x  = (const float*)d_in[0];   // [16384,256]
    const float* W1 = (const float*)d_in[1];   // [32,256,256]
    const float* b1 = (const float*)d_in[2];   // [32,256]
    const float* W2 = (const float*)d_in[3];   // [32,256,256]
    const float* b2 = (const float*)d_in[4];   // [32,256]
    const float* Wg = (const float*)d_in[5];   // [32,256]
    const float* bg = (const float*)d_in[6];   // [32]
    float* out = (float*)d_out;                // [16384,256]

    char* ws = (char*)d_ws;
    float*          wgt = (float*)ws;                              // 2 MB
    unsigned short* W1b = (unsigned short*)(ws + (2u << 20));      // 4 MB
    unsigned short* W2b = (unsigned short*)(ws + (6u << 20));      // 4 MB

    cvt_w<<<2048, 256, 0, stream>>>(W1, W2, W1b, W2b);
    gating_kernel<<<4096, 256, 0, stream>>>(x, Wg, bg, b2, wgt, out);
    moe_kernel<<<256, 512, 0, stream>>>(x, W1b, W2b, b1, wgt, out);
}

// Round 4
// 312.323 us; speedup vs baseline: 1.4412x; 1.4412x over previous
//
#include <hip/hip_runtime.h>
#include <hip/hip_bf16.h>

// ---------------------------------------------------------------------------
// MoE dense all-expert forward, MI355X / gfx950.  B=16384, D=H=O=256, E=32.
// Round 4: latency-oriented rebuild.
//  k0: cvt_w : W1,W2 f32 -> bf16, reordered into per-(expert, wave-slot, kb)
//      contiguous 4 KB chunks (each weight load = one coalesced 1 KB instr).
//  k1: moe   : 256 blocks x 512 thr. Per block (64 batch rows):
//      - inline f32 gating (softmax top-22), weights -> LDS gws
//      - crew0 (waves 0-3): h(e)^T = W1[e].x^T ; crew1 (waves 4-7):
//        out^T += W2[e-1].h(e-1)^T, bias2-init computed in-block
//      - weight stream register-double-buffered one kb-chunk ahead,
//        flowing across expert boundaries and barriers.
// ---------------------------------------------------------------------------

typedef __attribute__((ext_vector_type(8))) short bf16x8;   // 8 bf16 = 4 VGPRs
typedef __attribute__((ext_vector_type(4))) float f32x4;

__device__ __forceinline__ unsigned short f2bf(float f) {
    unsigned u = __builtin_bit_cast(unsigned, f);
    u += 0x7FFFu + ((u >> 16) & 1u);        // round-to-nearest-even
    return (unsigned short)(u >> 16);
}
__device__ __forceinline__ unsigned pack_bf16x2(float a, float b) {
    return (unsigned)f2bf(a) | ((unsigned)f2bf(b) << 16);
}

// 16B-chunk XOR swizzle for [64 rows][256 elem] bf16 tiles (index in ushorts)
#define LX(r, ch) (((r) << 8) + ((((ch) ^ ((r) & 7))) << 3))

// ------------------- W f32 -> bf16 convert + tile reorder ------------------
// Layout: chunk c = (e*8 + slot)*8 + kb  (slot=wave id; 0-3 -> W1 rows
// slot*64.., 4-7 -> W2 rows (slot-4)*64..). Chunk = 2048 bf16 = 4 KB,
// element order (t, lane, j): row = slot64 + t*16 + (lane&15),
// k = kb*32 + (lane>>4)*8 + j  — exactly the mfma_16x16x32 A-frag order.
__global__ __launch_bounds__(256) void cvt_w(const float* __restrict__ W1,
                                             const float* __restrict__ W2,
                                             unsigned short* __restrict__ Wr) {
    int T = blockIdx.x * 256 + threadIdx.x;          // 524288 threads
    int lane = T & 63, t = (T >> 6) & 3, kb = (T >> 8) & 7;
    int g = (T >> 11) & 7, e = T >> 14;
    int l15 = lane & 15, quad = lane >> 4;
    int row = (g & 3) * 64 + t * 16 + l15;
    const float* src = ((g < 4) ? W1 : W2) +
                       ((long)e * 256 + row) * 256 + kb * 32 + quad * 8;
    float4 v0 = ((const float4*)src)[0], v1 = ((const float4*)src)[1];
    uint4 o;
    o.x = pack_bf16x2(v0.x, v0.y); o.y = pack_bf16x2(v0.z, v0.w);
    o.z = pack_bf16x2(v1.x, v1.y); o.w = pack_bf16x2(v1.z, v1.w);
    ((uint4*)Wr)[T] = o;
}

// ------------------------------ fused MoE ----------------------------------
__global__ __launch_bounds__(512, 2) void moe_kernel(
    const float* __restrict__ x,
    const unsigned short* __restrict__ Wr,
    const float* __restrict__ bias1,
    const float* __restrict__ b2,
    const float* __restrict__ Wg,
    const float* __restrict__ bg,
    float* __restrict__ out)
{
    __shared__ __align__(16) unsigned short x_s[64 * 256];   // x tile, bf16
    __shared__ __align__(16) unsigned short h_s[64 * 256];   // h tile, bf16
    __shared__ float gws[64 * 33];                           // gate weights

    const int tid  = threadIdx.x;
    const int wv   = tid >> 6, lane = tid & 63;
    const int quad = lane >> 4, l15 = lane & 15;
    const int crew = wv >> 2, g = wv & 3;       // crew0 = GEMM1, crew1 = GEMM2
    const int row0 = blockIdx.x * 64;

    // ---- stage x tile: f32 global -> bf16 LDS (swizzled) ----
#pragma unroll
    for (int c = 0; c < 4; ++c) {
        int chunk = tid + c * 512;              // 2048 chunks of 8 elems
        int r = chunk >> 5, ch = chunk & 31;
        const float4* s = (const float4*)(x + (long)(row0 + r) * 256 + ch * 8);
        float4 v0 = s[0], v1 = s[1];
        uint4 o;
        o.x = pack_bf16x2(v0.x, v0.y); o.y = pack_bf16x2(v0.z, v0.w);
        o.z = pack_bf16x2(v1.x, v1.y); o.w = pack_bf16x2(v1.z, v1.w);
        *(uint4*)(&x_s[LX(r, ch)]) = o;
    }

    // ---- inline gating: 8 rows per wave, all f32 (matches reference) ----
    {
        const int e32 = lane & 31, half = lane >> 5;
        const float4* wg4 = (const float4*)(Wg + e32 * 256 + half * 128);
        float bgv = bg[e32];
        for (int i = 0; i < 8; ++i) {
            int lr = wv * 8 + i;
            const float4* xr4 = (const float4*)(x + (long)(row0 + lr) * 256 + half * 128);
            float acc = 0.f;
#pragma unroll
            for (int tt = 0; tt < 32; ++tt) {
                float4 w = wg4[tt], xv = xr4[tt];
                acc = fmaf(w.x, xv.x, acc); acc = fmaf(w.y, xv.y, acc);
                acc = fmaf(w.z, xv.z, acc); acc = fmaf(w.w, xv.w, acc);
            }
            acc += __shfl_xor(acc, 32);
            float score = (acc + bgv) / 2.71828182845904523f;   // TEMP = e

            float m = score;
#pragma unroll
            for (int d = 16; d >= 1; d >>= 1) m = fmaxf(m, __shfl_xor(m, d));
            float p = expf(score - m);
            float ps = p;
#pragma unroll
            for (int d = 16; d >= 1; d >>= 1) ps += __shfl_xor(ps, d);
            float prob = p / ps;

            int rank = 0;
#pragma unroll
            for (int j = 0; j < 32; ++j) {
                float pj = __shfl(prob, j);
                rank += (pj > prob || (pj == prob && j < e32)) ? 1 : 0;
            }
            float kept = (rank < 22) ? prob : 0.f;
            float wsum = kept;
#pragma unroll
            for (int d = 16; d >= 1; d >>= 1) wsum += __shfl_xor(wsum, d);
            float weight = kept / (wsum + 1e-8f);

            if (half == 0) gws[lr * 33 + e32] = weight;
        }
    }

    __syncthreads();   // x_s + gws ready

    // ---- crew1: out^T accumulators, init = sum_e gw*b2 (in-block bias2) ----
    f32x4 oacc[4][4];                           // [ot][rt]
#pragma unroll
    for (int ot = 0; ot < 4; ++ot)
#pragma unroll
        for (int rt = 0; rt < 4; ++rt) {
            f32x4 z = {0.f, 0.f, 0.f, 0.f};
            oacc[ot][rt] = z;
        }
    if (crew == 1) {
        for (int ee = 0; ee < 32; ++ee) {
            float gv[4];
#pragma unroll
            for (int rt = 0; rt < 4; ++rt) gv[rt] = gws[(rt * 16 + l15) * 33 + ee];
#pragma unroll
            for (int ot = 0; ot < 4; ++ot) {
                float4 bb = *(const float4*)(b2 + ee * 256 + g * 64 + ot * 16 + quad * 4);
#pragma unroll
                for (int rt = 0; rt < 4; ++rt) {
                    oacc[ot][rt][0] = fmaf(gv[rt], bb.x, oacc[ot][rt][0]);
                    oacc[ot][rt][1] = fmaf(gv[rt], bb.y, oacc[ot][rt][1]);
                    oacc[ot][rt][2] = fmaf(gv[rt], bb.z, oacc[ot][rt][2]);
                    oacc[ot][rt][3] = fmaf(gv[rt], bb.w, oacc[ot][rt][3]);
                }
            }
        }
    }

    // ---- preload weight chunk (expert 0, slot wv, kb 0) into registers ----
    bf16x8 buf[4];
    {
        const unsigned short* p0 = Wr + ((long)wv * 8) * 2048;
#pragma unroll
        for (int t = 0; t < 4; ++t)
            buf[t] = *(const bf16x8*)(p0 + t * 512 + lane * 8);
    }

    // ---- expert pipeline: crew0 computes e, crew1 computes e-1 ----
    for (int e = 0; e <= 32; ++e) {
        f32x4 hacc[4][4];                       // crew0 transient [ht][rt]
        if (crew == 0) {
            if (e < 32) {
#pragma unroll
                for (int ht = 0; ht < 4; ++ht)
#pragma unroll
                    for (int rt = 0; rt < 4; ++rt) {
                        f32x4 z = {0.f, 0.f, 0.f, 0.f};
                        hacc[ht][rt] = z;
                    }
                const unsigned short* wcur = Wr + ((long)(e * 8 + wv) * 8) * 2048;
                const unsigned short* wnxt = Wr + ((long)((e + 1) * 8 + wv) * 8) * 2048;
#pragma unroll
                for (int kb = 0; kb < 8; ++kb) {
                    bf16x8 a[4];
#pragma unroll
                    for (int t = 0; t < 4; ++t) a[t] = buf[t];
                    const unsigned short* np = (kb < 7) ? (wcur + (kb + 1) * 2048) : wnxt;
#pragma unroll
                    for (int t = 0; t < 4; ++t)
                        buf[t] = *(const bf16x8*)(np + t * 512 + lane * 8);
                    bf16x8 bb[4];
#pragma unroll
                    for (int rt = 0; rt < 4; ++rt)
                        bb[rt] = *(const bf16x8*)(&x_s[LX(rt * 16 + l15, kb * 4 + quad)]);
#pragma unroll
                    for (int ht = 0; ht < 4; ++ht)
#pragma unroll
                        for (int rt = 0; rt < 4; ++rt)
                            hacc[ht][rt] = __builtin_amdgcn_mfma_f32_16x16x32_bf16(
                                a[ht], bb[rt], hacc[ht][rt], 0, 0, 0);
                }
            }
        } else {
            if (e >= 1) {
                const int me = e - 1;
                const unsigned short* wcur = Wr + ((long)(me * 8 + wv) * 8) * 2048;
                const unsigned short* wnxt = Wr + ((long)((me + 1) * 8 + wv) * 8) * 2048;
#pragma unroll
                for (int kb = 0; kb < 8; ++kb) {
                    bf16x8 a[4];
#pragma unroll
                    for (int t = 0; t < 4; ++t) a[t] = buf[t];
                    const unsigned short* np = (kb < 7) ? (wcur + (kb + 1) * 2048) : wnxt;
#pragma unroll
                    for (int t = 0; t < 4; ++t)
                        buf[t] = *(const bf16x8*)(np + t * 512 + lane * 8);
                    bf16x8 bb[4];
#pragma unroll
                    for (int rt = 0; rt < 4; ++rt)
                        bb[rt] = *(const bf16x8*)(&h_s[LX(rt * 16 + l15, kb * 4 + quad)]);
#pragma unroll
                    for (int ot = 0; ot < 4; ++ot)
#pragma unroll
                        for (int rt = 0; rt < 4; ++rt)
                            oacc[ot][rt] = __builtin_amdgcn_mfma_f32_16x16x32_bf16(
                                a[ot], bb[rt], oacc[ot][rt], 0, 0, 0);
                }
            }
        }

        __syncthreads();   // crew1 done reading h_s(e-1); crew0 hacc(e) ready

        if (crew == 0 && e < 32) {
            // epilogue: +b1, relu, * gate weight, packed b64 -> h_s
            float4 bv[4]; float gw[4];
#pragma unroll
            for (int ht = 0; ht < 4; ++ht)
                bv[ht] = *(const float4*)(bias1 + e * 256 + g * 64 + ht * 16 + quad * 4);
#pragma unroll
            for (int rt = 0; rt < 4; ++rt)
                gw[rt] = gws[(rt * 16 + l15) * 33 + e];
#pragma unroll
            for (int ht = 0; ht < 4; ++ht) {
                int hb = g * 64 + ht * 16 + quad * 4;   // 4 consecutive h-cols
                int ch = hb >> 3, off = hb & 7;
#pragma unroll
                for (int rt = 0; rt < 4; ++rt) {
                    int r = rt * 16 + l15;
                    float v0 = fmaxf(hacc[ht][rt][0] + bv[ht].x, 0.f) * gw[rt];
                    float v1 = fmaxf(hacc[ht][rt][1] + bv[ht].y, 0.f) * gw[rt];
                    float v2 = fmaxf(hacc[ht][rt][2] + bv[ht].z, 0.f) * gw[rt];
                    float v3 = fmaxf(hacc[ht][rt][3] + bv[ht].w, 0.f) * gw[rt];
                    uint2 p;
                    p.x = pack_bf16x2(v0, v1);
                    p.y = pack_bf16x2(v2, v3);
                    *(uint2*)(&h_s[(r << 8) + ((ch ^ (r & 7)) << 3) + off]) = p;
                }
            }
        }

        __syncthreads();   // h_s(e) final, visible to crew1 next phase
    }

    // ---- final store: out^T frags -> out ----
    if (crew == 1) {
#pragma unroll
        for (int ot = 0; ot < 4; ++ot)
#pragma unroll
            for (int rt = 0; rt < 4; ++rt)
                *(f32x4*)(out + (long)(row0 + rt * 16 + l15) * 256 +
                          g * 64 + ot * 16 + quad * 4) = oacc[ot][rt];
    }
}

// ------------------------------- launch ------------------------------------
extern "C" void kernel_launch(void* const* d_in, const int* in_sizes, int n_in,
                              void* d_out, int out_size, void* d_ws, size_t ws_size,
                              hipStream_t stream) {
    (void)in_sizes; (void)n_in; (void)out_size; (void)ws_size;
    const float* x  = (const float*)d_in[0];   // [16384,256]
    const float* W1 = (const float*)d_in[1];   // [32,256,256]
    const float* b1 = (const float*)d_in[2];   // [32,256]
    const float* W2 = (const float*)d_in[3];   // [32,256,256]
    const float* b2 = (const float*)d_in[4];   // [32,256]
    const float* Wg = (const float*)d_in[5];   // [32,256]
    const float* bg = (const float*)d_in[6];   // [32]
    float* out = (float*)d_out;                // [16384,256]

    // ws: Wr = 33 experts (32 real + 1 prefetch-overrun pad) x 256 KB
    unsigned short* Wr = (unsigned short*)d_ws;

    cvt_w<<<2048, 256, 0, stream>>>(W1, W2, Wr);
    moe_kernel<<<256, 512, 0, stream>>>(x, Wr, b1, b2, Wg, bg, out);
}